// Round 4
// baseline (272.614 us; speedup 1.0000x reference)
//
#include <hip/hip_runtime.h>
#include <hip/hip_bf16.h>

// Problem constants (from reference)
#define BATCH 16
#define HH 1024
#define WW 2048
#define HWPIX (HH * WW)            // 2,097,152 pixels per batch
#define NID 255                    // ids 101..355 -> index 0..254

#define THREADS 1024
#define SLICES 32                  // blocks per batch; 16*32 = 512 blocks = 2/CU
#define PIX_PER_BLOCK (HWPIX / SLICES)        // 65536 (32 rows of 2048)
#define ROWS_PER_BLOCK (PIX_PER_BLOCK / WW)   // 32
#define ITERS (PIX_PER_BLOCK / (THREADS * 4)) // 16 (2 rows per iter)

#define SLOTS 8                    // rows in flight (row mod 8)
#define COLS 8                     // lane-groups per (id,row)
#define IDSTRIDE 72                // SLOTS*COLS + 8 pad words -> id*72 rotates banks
#define ROUNDS 4                   // flush every 8 rows (4 iters)

// Cell packing (u32): [cnt:9 bits at 23..31 | sx:23 bits at 0..22]
// Worst case per cell = one row x one 8-lane col-group = 256 px:
//   cnt <= 256 < 512 ; sx <= 256*2047 = 524,032 < 2^23.  Exact for ANY data.
// sy is derived at flush: cell's row is known (slot = row & 7, round base).

__global__ __launch_bounds__(THREADS) void accum_kernel(
    const float* __restrict__ logits, const int* __restrict__ label,
    unsigned* __restrict__ g_cnt, unsigned* __restrict__ g_sx,
    unsigned* __restrict__ g_sy, double* __restrict__ g_exp)
{
    __shared__ unsigned tab[NID * IDSTRIDE];   // 73,440 B -> 2 blocks/CU
    __shared__ double exp_lds[16];

    const int tid  = threadIdx.x;
    const int lane = tid & 63;
    const int col  = lane & 7;
    const int batch = blockIdx.x >> 5;
    const int slice = blockIdx.x & 31;

    for (int i = tid; i < NID * IDSTRIDE; i += THREADS) tab[i] = 0u;
    __syncthreads();

    const float4* lg4 = (const float4*)logits + (size_t)batch * (HWPIX / 4) + slice * (PIX_PER_BLOCK / 4);
    const int4*   lb4 = (const int4*)label   + (size_t)batch * (HWPIX / 4) + slice * (PIX_PER_BLOCK / 4);

    float es = 0.f;
    unsigned cnt_a = 0, sx_a = 0, sy_a = 0;    // per-thread id-quarter accumulators
    const int fid  = tid >> 2;                 // flush: id index (0..254)
    const int fsub = tid & 3;                  // flush: quarter (2 slots x 8 cols)

    for (int rnd = 0; rnd < ROUNDS; ++rnd) {
#pragma unroll
        for (int ii = 0; ii < 4; ++ii) {
            const int i = rnd * 4 + ii;
            const int g = i * THREADS + tid;          // float4-group within slice
            const float4 f  = lg4[g];
            const int4   lb = lb4[g];
            es += __expf(f.x) + __expf(f.y) + __expf(f.z) + __expf(f.w);
            const int p0 = g << 2;                    // pixel index within slice
            const int yr = p0 >> 11;                  // local row (0..31)
            const int x0 = p0 & 2047;
            const unsigned sbase = (unsigned)((yr & 7) * COLS + col);
            if (lb.x > 100) atomicAdd(&tab[(lb.x - 101) * IDSTRIDE + sbase], (1u << 23) | (unsigned)(x0 + 0));
            if (lb.y > 100) atomicAdd(&tab[(lb.y - 101) * IDSTRIDE + sbase], (1u << 23) | (unsigned)(x0 + 1));
            if (lb.z > 100) atomicAdd(&tab[(lb.z - 101) * IDSTRIDE + sbase], (1u << 23) | (unsigned)(x0 + 2));
            if (lb.w > 100) atomicAdd(&tab[(lb.w - 101) * IDSTRIDE + sbase], (1u << 23) | (unsigned)(x0 + 3));
        }
        __syncthreads();
        // flush + zero this round's 8 rows (slots 0..7)
        if (tid < NID * 4) {
            unsigned* cp = &tab[fid * IDSTRIDE + fsub * 16];
#pragma unroll
            for (int c = 0; c < 16; ++c) {
                const unsigned v = cp[c];
                cp[c] = 0u;
                const unsigned cnt = v >> 23;
                const unsigned sx  = v & 0x7FFFFFu;
                const unsigned row = (unsigned)(rnd * 8 + fsub * 2 + (c >> 3)); // local row
                cnt_a += cnt;
                sx_a  += sx;
                sy_a  += row * cnt;
            }
        }
        __syncthreads();
    }

    // exp partial: wave shuffle reduce -> LDS -> ONE f64 atomic per block
    for (int off = 32; off > 0; off >>= 1) es += __shfl_down(es, off, 64);
    if (lane == 0) exp_lds[tid >> 6] = (double)es;
    __syncthreads();
    if (tid == 0) {
        double t = 0.0;
        for (int w = 0; w < 16; ++w) t += exp_lds[w];
        atomicAdd(g_exp, t);
    }

    // global flush: 4 threads per id, 3 u32 atomics each
    if (tid < NID * 4 && cnt_a) {
        const unsigned base_row = slice * ROWS_PER_BLOCK;
        atomicAdd(&g_cnt[batch * NID + fid], cnt_a);
        atomicAdd(&g_sx [batch * NID + fid], sx_a);
        atomicAdd(&g_sy [batch * NID + fid], sy_a + base_row * cnt_a);
    }
}

__global__ __launch_bounds__(256) void finalize_kernel(
    const float* __restrict__ logits, const unsigned* __restrict__ g_cnt,
    const unsigned* __restrict__ g_sx, const unsigned* __restrict__ g_sy,
    const double* __restrict__ g_exp, float* __restrict__ out)
{
    const int tid = threadIdx.x;
    float s = 0.f;
    if (tid < NID) {                    // id = 101 + tid
        for (int b = 0; b < BATCH; ++b) {
            const unsigned cnt = g_cnt[b * NID + tid];
            if (cnt) {
                const float fc = (float)cnt;
                // identical f32 divide + truncation as the reference
                const int cx = (int)((float)g_sx[b * NID + tid] / fc);
                const int cy = (int)((float)g_sy[b * NID + tid] / fc);
                s += logits[(size_t)b * HWPIX + (size_t)cy * WW + cx];
            }
        }
    }
    __shared__ float red[256];
    red[tid] = s;
    __syncthreads();
    for (int off = 128; off > 0; off >>= 1) {
        if (tid < off) red[tid] += red[tid + off];
        __syncthreads();
    }
    if (tid == 0) {
        const double int_loss = *g_exp / (double)((double)BATCH * (double)HWPIX);
        out[0] = (float)(int_loss - (double)red[0] / (double)BATCH);
    }
}

extern "C" void kernel_launch(void* const* d_in, const int* in_sizes, int n_in,
                              void* d_out, int out_size, void* d_ws, size_t ws_size,
                              hipStream_t stream) {
    const float* logits = (const float*)d_in[0];
    const int*   label  = (const int*)d_in[1];
    float* out = (float*)d_out;

    unsigned* g_cnt = (unsigned*)d_ws;
    unsigned* g_sx  = g_cnt + BATCH * NID;
    unsigned* g_sy  = g_sx  + BATCH * NID;
    double*   g_exp = (double*)(g_sy + BATCH * NID);   // 48,960 B offset, 8-aligned

    // zero accumulators every call (harness does not re-poison between replays)
    hipMemsetAsync(d_ws, 0, (size_t)BATCH * NID * 3 * sizeof(unsigned) + sizeof(double), stream);

    accum_kernel<<<BATCH * SLICES, THREADS, 0, stream>>>(logits, label, g_cnt, g_sx, g_sy, g_exp);
    finalize_kernel<<<1, 256, 0, stream>>>(logits, g_cnt, g_sx, g_sy, g_exp, out);
}

// Round 5
// 105.567 us; speedup vs baseline: 2.5824x; 2.5824x over previous
//
#include <hip/hip_runtime.h>
#include <hip/hip_bf16.h>

// Problem constants (from reference)
#define BATCH 16
#define HH 1024
#define WW 2048
#define HWPIX (HH * WW)            // 2,097,152 pixels per batch
#define NID 255                    // ids 101..355 -> index 0..254

#define THREADS 1024
#define SW 256                     // strip width (px)  -> x = X0 + 4*lane + s
#define SR 64                      // strip rows
#define SPB (WW / SW)              // 8 strips across
#define VCH (HH / SR)              // 16 row-bands
#define ITERS 4                    // 4 iters x 4 px x 1024 thr = 16384 = SW*SR

#define TCOLS 128                  // cols per id: lane + 64*(wave&1)
#define TWORDS (NID * TCOLS)       // 32640 words = 130,560 B
#define PSTR 13                    // part stride (coprime-ish to 32 for banks)

typedef unsigned u32;

// Cell u32 per (id, lane, wave-parity):
//   [0,13)  sum(yr - par)  (<= 128*62 = 7936  < 8192)
//   [13,22) sum(slot)      (<= 128*3  = 384   < 512)
//   [22,31) count          (<= 8w*4i*4s = 128 < 512)
// Exposure bound 128 px/cell is structural -> no overflow for ANY data.
// Within an atomic instr: 64 distinct cols -> zero same-address; word addr =
// id*128 + lane -> bank = lane&31 -> exactly 2 lanes/bank (conflict-free).

__global__ __launch_bounds__(THREADS) void accum_kernel(
    const float* __restrict__ logits, const int* __restrict__ label,
    u32* __restrict__ g_cnt, u32* __restrict__ g_sx,
    u32* __restrict__ g_sy, double* __restrict__ g_exp)
{
    __shared__ u32 tab[TWORDS];          // 130,560 B
    __shared__ u32 part[NID * PSTR];     // 13,260 B
    __shared__ double exp_lds[16];

    const int tid  = threadIdx.x;
    const int w    = tid >> 6;
    const int lane = tid & 63;
    const int par  = w & 1;
    const int col  = lane + (par << 6);

    const int batch = blockIdx.x >> 7;   // 128 blocks per batch
    const int rem   = blockIdx.x & 127;
    const int vch   = rem >> 3;          // 0..15 row-band
    const int strip = rem & 7;           // 0..7

    for (int i = tid; i < TWORDS; i += THREADS) tab[i] = 0u;
    __syncthreads();

    const float4* lg4 = (const float4*)logits + (size_t)batch * (HWPIX/4) + strip * (SW/4);
    const int4*   lb4 = (const int4*)label   + (size_t)batch * (HWPIX/4) + strip * (SW/4);

    float es = 0.f;
#pragma unroll
    for (int i = 0; i < ITERS; ++i) {
        const int yr = i * 16 + w;                       // local row 0..63
        const int g  = (vch * SR + yr) * (WW/4) + lane;  // float4 index
        const float4 f  = lg4[g];
        const int4   lb = lb4[g];
        es += __expf(f.x) + __expf(f.y) + __expf(f.z) + __expf(f.w);
        const u32 yq = (u32)(yr - par);
        if (lb.x > 100) atomicAdd(&tab[(lb.x-101)*TCOLS + col], (1u<<22) | (0u<<13) | yq);
        if (lb.y > 100) atomicAdd(&tab[(lb.y-101)*TCOLS + col], (1u<<22) | (1u<<13) | yq);
        if (lb.z > 100) atomicAdd(&tab[(lb.z-101)*TCOLS + col], (1u<<22) | (2u<<13) | yq);
        if (lb.w > 100) atomicAdd(&tab[(lb.w-101)*TCOLS + col], (1u<<22) | (3u<<13) | yq);
    }

    // exp partial: wave shuffle reduce -> LDS
    for (int off = 32; off > 0; off >>= 1) es += __shfl_down(es, off, 64);
    if (lane == 0) exp_lds[w] = (double)es;
    __syncthreads();

    // stage A: thread (id = tid>>2, quarter q = tid&3) reduces 32 cols
    {
        const int id = tid >> 2;
        const int q  = tid & 3;
        if (id < NID) {
            u32 cnt_a = 0, sx_a = 0, sy_a = 0;
            const u32* rowp = &tab[id * TCOLS + q * 32];
            for (int j = 0; j < 32; ++j) {
                const int jj = (j + id) & 31;            // bank de-swizzle
                const u32 v   = rowp[jj];
                const u32 cnt = v >> 22;
                const u32 sdx = (v >> 13) & 0x1FFu;
                const u32 sye = v & 0x1FFFu;
                const int c   = q * 32 + jj;             // col 0..127
                cnt_a += cnt;
                sx_a  += (u32)((c & 63) << 2) * cnt + sdx;      // 4*lane*cnt + sum(s)
                sy_a  += sye + (u32)(c >> 6) * cnt;             // + par*cnt
            }
            part[id * PSTR + q*3 + 0] = cnt_a;
            part[id * PSTR + q*3 + 1] = sx_a;
            part[id * PSTR + q*3 + 2] = sy_a;
        }
    }
    __syncthreads();

    if (tid == 0) {
        double t = 0.0;
        for (int k = 0; k < 16; ++k) t += exp_lds[k];
        atomicAdd(g_exp, t);
    }

    // stage B: one thread per id, combine quarters, 3 global atomics
    if (tid < NID) {
        u32 cnt_t = 0, sx_t = 0, sy_t = 0;
        for (int q = 0; q < 4; ++q) {
            cnt_t += part[tid * PSTR + q*3 + 0];
            sx_t  += part[tid * PSTR + q*3 + 1];
            sy_t  += part[tid * PSTR + q*3 + 2];
        }
        if (cnt_t) {
            const u32 X0 = (u32)(strip * SW);
            const u32 Y0 = (u32)(vch * SR);
            atomicAdd(&g_cnt[batch*NID + tid], cnt_t);
            atomicAdd(&g_sx [batch*NID + tid], sx_t + X0 * cnt_t);
            atomicAdd(&g_sy [batch*NID + tid], sy_t + Y0 * cnt_t);
        }
    }
}

__global__ __launch_bounds__(256) void finalize_kernel(
    const float* __restrict__ logits, const u32* __restrict__ g_cnt,
    const u32* __restrict__ g_sx, const u32* __restrict__ g_sy,
    const double* __restrict__ g_exp, float* __restrict__ out)
{
    const int tid = threadIdx.x;
    float s = 0.f;
    if (tid < NID) {                    // id = 101 + tid
        for (int b = 0; b < BATCH; ++b) {
            const u32 cnt = g_cnt[b * NID + tid];
            if (cnt) {
                const float fc = (float)cnt;
                // identical f32 divide + truncation as the reference
                const int cx = (int)((float)g_sx[b * NID + tid] / fc);
                const int cy = (int)((float)g_sy[b * NID + tid] / fc);
                s += logits[(size_t)b * HWPIX + (size_t)cy * WW + cx];
            }
        }
    }
    __shared__ float red[256];
    red[tid] = s;
    __syncthreads();
    for (int off = 128; off > 0; off >>= 1) {
        if (tid < off) red[tid] += red[tid + off];
        __syncthreads();
    }
    if (tid == 0) {
        const double int_loss = *g_exp / (double)((double)BATCH * (double)HWPIX);
        out[0] = (float)(int_loss - (double)red[0] / (double)BATCH);
    }
}

extern "C" void kernel_launch(void* const* d_in, const int* in_sizes, int n_in,
                              void* d_out, int out_size, void* d_ws, size_t ws_size,
                              hipStream_t stream) {
    const float* logits = (const float*)d_in[0];
    const int*   label  = (const int*)d_in[1];
    float* out = (float*)d_out;

    u32*    g_cnt = (u32*)d_ws;
    u32*    g_sx  = g_cnt + BATCH * NID;
    u32*    g_sy  = g_sx  + BATCH * NID;
    double* g_exp = (double*)(g_sy + BATCH * NID);   // 48,960 B offset, 8-aligned

    // zero accumulators every call (harness does not re-poison between replays)
    hipMemsetAsync(d_ws, 0, (size_t)BATCH * NID * 3 * sizeof(u32) + sizeof(double), stream);

    accum_kernel<<<BATCH * VCH * SPB, THREADS, 0, stream>>>(logits, label, g_cnt, g_sx, g_sy, g_exp);
    finalize_kernel<<<1, 256, 0, stream>>>(logits, g_cnt, g_sx, g_sy, g_exp, out);
}